// Round 1
// baseline (5879.923 us; speedup 1.0000x reference)
//
#include <hip/hip_runtime.h>
#include <stdint.h>

#define BDIM 64
#define TDIM 512
#define EDIM 512
#define HDIM 512

typedef __attribute__((ext_vector_type(8))) short bf16x8;
typedef __attribute__((ext_vector_type(4))) float f32x4;
typedef __attribute__((ext_vector_type(4))) unsigned int u32x4;
typedef __attribute__((ext_vector_type(4))) unsigned short u16x4;

static __device__ __forceinline__ unsigned short f2bf(float f) {
  union { float f; uint32_t u; } c; c.f = f;
  uint32_t u = c.u;
  uint32_t r = u + 0x7fffu + ((u >> 16) & 1u);
  return (unsigned short)(r >> 16);
}
static __device__ __forceinline__ float bf2f(unsigned short s) {
  union { uint32_t u; float f; } c; c.u = ((uint32_t)s) << 16;
  return c.f;
}

// swizzle for 1KB-row tiles (512 bf16 per row)
#define SWZ(row, byteInRow) ((((row)*1024) + (byteInRow)) ^ ((((row)&7))<<4))
// swizzle for 128B-row tiles (64 bf16 per row)
#define SWZA(row, byteInRow) ((((row)*128) + (byteInRow)) ^ ((((row)&7))<<4))

// ---------------- small utility kernels ----------------

__global__ void sentinel_kern(float* out, int n) {
  for (int i = blockIdx.x * blockDim.x + threadIdx.x; i < n; i += gridDim.x * blockDim.x)
    out[i] = -12345.0f;
}

__global__ void conv_w(const float* __restrict__ Wz, const float* __restrict__ Wr,
                       const float* __restrict__ Wh,
                       unsigned short* __restrict__ Wxb, unsigned short* __restrict__ Whb) {
  int idx = blockIdx.x * 256 + threadIdx.x;
  if (idx >= 3 * 512 * 1024) return;
  int g = idx >> 19;
  int rem = idx & 524287;
  int j = rem >> 10, k = rem & 1023;
  const float* W = (g == 0) ? Wz : (g == 1) ? Wr : Wh;
  unsigned short b = f2bf(W[(size_t)j * 1024 + k]);
  if (k < 512) Wxb[((size_t)g * 512 + j) * 512 + k] = b;
  else         Whb[((size_t)g * 512 + j) * 512 + (k - 512)] = b;
}

__global__ void conv_x(const float* __restrict__ x, unsigned short* __restrict__ xb, int n4) {
  for (int i = blockIdx.x * blockDim.x + threadIdx.x; i < n4; i += gridDim.x * blockDim.x) {
    f32x4 v = ((const f32x4*)x)[i];
    u16x4 o;
    o[0] = f2bf(v[0]); o[1] = f2bf(v[1]); o[2] = f2bf(v[2]); o[3] = f2bf(v[3]);
    ((u16x4*)xb)[i] = o;
  }
}

__global__ void add_out(float* __restrict__ out, const float* __restrict__ Hb, int n4) {
  for (int i = blockIdx.x * blockDim.x + threadIdx.x; i < n4; i += gridDim.x * blockDim.x) {
    f32x4 a = ((const f32x4*)out)[i];
    f32x4 b = ((const f32x4*)Hb)[i];
    ((f32x4*)out)[i] = a + b;
  }
}

// ---------------- phase A: G = x @ Wx^T + bias  (bf16 MFMA GEMM) ----------------
// M = B*T = 32768 (row m = b*T+t), N = 1536 (n = gate*512 + j), K = 512

__global__ __launch_bounds__(256, 2)
void gru_xproj(const unsigned short* __restrict__ xb,
               const unsigned short* __restrict__ Wxb,
               const float* __restrict__ bz, const float* __restrict__ br,
               const float* __restrict__ bh,
               void* __restrict__ Gv, int g32) {
  __shared__ __align__(16) unsigned short lA[128 * 64];
  __shared__ __align__(16) unsigned short lB[128 * 64];
  const int tid = threadIdx.x;
  const int m0 = blockIdx.x * 128;
  const int n0 = blockIdx.y * 128;
  const int w = tid >> 6, lane = tid & 63, cl = lane & 15, q = lane >> 4;
  const int wr = w >> 1, wc = w & 1;
  f32x4 acc[4][4];
#pragma unroll
  for (int i = 0; i < 4; i++)
#pragma unroll
    for (int j = 0; j < 4; j++) acc[i][j] = (f32x4){0.f, 0.f, 0.f, 0.f};

  for (int ko = 0; ko < 8; ko++) {
    int k0 = ko * 64;
#pragma unroll
    for (int cc = 0; cc < 4; cc++) {
      int qq = tid * 4 + cc;
      int row = qq >> 3, kc = qq & 7;
      u32x4 va = *(const u32x4*)(xb + ((size_t)(m0 + row) * EDIM + k0 + kc * 8));
      *(u32x4*)((char*)lA + SWZA(row, kc * 16)) = va;
      u32x4 vb = *(const u32x4*)(Wxb + ((size_t)(n0 + row) * EDIM + k0 + kc * 8));
      *(u32x4*)((char*)lB + SWZA(row, kc * 16)) = vb;
    }
    __syncthreads();
#pragma unroll
    for (int ks = 0; ks < 2; ks++) {
      bf16x8 af[4], bfv[4];
#pragma unroll
      for (int i = 0; i < 4; i++) {
        int rl = wr * 64 + i * 16 + cl;
        af[i] = *(const bf16x8*)((char*)lA + SWZA(rl, ks * 64 + q * 16));
      }
#pragma unroll
      for (int j = 0; j < 4; j++) {
        int rl = wc * 64 + j * 16 + cl;
        bfv[j] = *(const bf16x8*)((char*)lB + SWZA(rl, ks * 64 + q * 16));
      }
#pragma unroll
      for (int i = 0; i < 4; i++)
#pragma unroll
        for (int j = 0; j < 4; j++)
          acc[i][j] = __builtin_amdgcn_mfma_f32_16x16x32_bf16(af[i], bfv[j], acc[i][j], 0, 0, 0);
    }
    __syncthreads();
  }
  const int g = n0 >> 9;
  const float* bias = (g == 0) ? bz : (g == 1) ? br : bh;
  float* Gf = (float*)Gv;
  unsigned short* Gb = (unsigned short*)Gv;
#pragma unroll
  for (int i = 0; i < 4; i++) {
#pragma unroll
    for (int j = 0; j < 4; j++) {
      int n = n0 + wc * 64 + j * 16 + cl;
      float bv = bias[n & 511];
#pragma unroll
      for (int ii = 0; ii < 4; ii++) {
        int m = m0 + wr * 64 + i * 16 + q * 4 + ii;
        float v = acc[i][j][ii] + bv;
        size_t gi = (size_t)m * 1536 + n;
        if (g32) Gf[gi] = v; else Gb[gi] = f2bf(v);
      }
    }
  }
}

// ---------------- persistent bidirectional recurrence ----------------
// 128 wgs: bid = cg*8 + gid; gid = dir*4 + bg (8 groups of 16 wgs each).
// Per wg: batches bg*16..+15 (M=16), columns j0=cg*32..+31 for all 3 gates.
// LDS: 6 weight tiles [16 cols][512 k] (96KB) + A_h + A_rh tiles + hprev.

__device__ __forceinline__ void gbar(unsigned int* ctr, unsigned int& ep, int tid) {
  __syncthreads();
  if (tid == 0) {
    ep++;
    unsigned int target = ep * 16u;
    __hip_atomic_fetch_add(ctr, 1u, __ATOMIC_RELEASE, __HIP_MEMORY_SCOPE_AGENT);
    while (__hip_atomic_load(ctr, __ATOMIC_RELAXED, __HIP_MEMORY_SCOPE_AGENT) < target)
      __builtin_amdgcn_s_sleep(1);
    (void)__hip_atomic_load(ctr, __ATOMIC_ACQUIRE, __HIP_MEMORY_SCOPE_AGENT);
  }
  __syncthreads();
}

__global__ __launch_bounds__(256, 1)
void gru_persist(const void* __restrict__ Gv, int g32,
                 const float* __restrict__ h0,
                 unsigned short* __restrict__ Hst,
                 unsigned short* __restrict__ RHst,
                 unsigned int* __restrict__ ctrs,
                 float* __restrict__ outp,
                 float* __restrict__ Hb,
                 const unsigned short* __restrict__ Whb) {
  __shared__ __align__(16) unsigned short lds_w[6 * 16 * 512];   // 96KB
  __shared__ __align__(16) unsigned short lds_ah[16 * 512];      // 16KB
  __shared__ __align__(16) unsigned short lds_arh[16 * 512];     // 16KB
  __shared__ float lds_hprev[16 * 32];                            // 2KB

  const int tid = threadIdx.x;
  const int bid = blockIdx.x;
  const int gid = bid & 7;
  const int cg = bid >> 3;
  const int dir = gid >> 2;
  const int bg = gid & 3;
  const int j0 = cg * 32;
  const int w = tid >> 6;
  const int lane = tid & 63;
  const int c = lane & 15;
  const int q = lane >> 4;
  unsigned int* ctr = &ctrs[gid * 16];

  // load weight tiles (one-time): nt = gate*2+sub, cols j0+sub*16+col
  for (int qk = tid; qk < 6144; qk += 256) {
    int nt = qk >> 10;
    int cin = qk & 1023;
    int col = cin & 15;
    int kc = cin >> 4;   // 0..63 (16B chunk)
    int g = nt >> 1, sub = nt & 1;
    int jglob = j0 + sub * 16 + col;
    u32x4 v = *(const u32x4*)(Whb + (((size_t)g * 512 + jglob) * 512 + kc * 8));
    *(u32x4*)((char*)lds_w + nt * 16384 + SWZ(col, kc * 16)) = v;
  }

  // init hprev (fp32, local cols) and Hst (bf16, agent-coherent)
#pragma unroll
  for (int ii = 0; ii < 2; ii++) {
    int idx = tid * 2 + ii;
    int row = idx >> 5, jl = idx & 31;
    int b = bg * 16 + row, j = j0 + jl;
    float v = h0[(size_t)b * HDIM + j];
    lds_hprev[row * 32 + jl] = v;
    __hip_atomic_store(&Hst[((size_t)dir * 64 + b) * 512 + j], f2bf(v),
                       __ATOMIC_RELAXED, __HIP_MEMORY_SCOPE_AGENT);
  }

  unsigned int ep = 0;
  gbar(ctr, ep, tid);

  const float* Gf = (const float*)Gv;
  const unsigned short* Gb = (const unsigned short*)Gv;
  const int sub = w & 1;
  const int jn = j0 + sub * 16 + c;
  const int gateA = (w < 2) ? 0 : 1;

  for (int s = 0; s < TDIM; s++) {
    int t = dir ? (TDIM - 1 - s) : s;

    // prefetch G values for this step (independent of staging)
    f32x4 gA, gC;
#pragma unroll
    for (int i = 0; i < 4; i++) {
      int b = bg * 16 + q * 4 + i;
      size_t mrow = (size_t)b * TDIM + t;
      size_t giA = (mrow * 3 + gateA) * HDIM + jn;
      gA[i] = g32 ? Gf[giA] : bf2f(Gb[giA]);
      if (w < 2) {
        size_t giC = (mrow * 3 + 2) * HDIM + jn;
        gC[i] = g32 ? Gf[giC] : bf2f(Gb[giC]);
      }
    }

    // stage A_h (h state, bf16) into LDS
    {
      int row = tid & 15;
      int cb = (tid >> 4) * 64;
      const u32x4* src = (const u32x4*)((const char*)Hst +
                          ((size_t)(dir * 64 + bg * 16 + row) * 512) * 2 + cb);
      u32x4 v0 = src[0], v1 = src[1], v2 = src[2], v3 = src[3];
      char* dst = (char*)lds_ah;
      *(u32x4*)(dst + SWZ(row, cb + 0))  = v0;
      *(u32x4*)(dst + SWZ(row, cb + 16)) = v1;
      *(u32x4*)(dst + SWZ(row, cb + 32)) = v2;
      *(u32x4*)(dst + SWZ(row, cb + 48)) = v3;
    }
    __syncthreads();

    // P1: wave w computes tile nt=w (z: 0,1 ; r: 2,3), K=512
    f32x4 acc = (f32x4){0.f, 0.f, 0.f, 0.f};
    {
      const char* wb = (const char*)lds_w + w * 16384;
      const char* ab = (const char*)lds_ah;
#pragma unroll
      for (int ks = 0; ks < 16; ks++) {
        int kb = ks * 64 + q * 16;
        bf16x8 af = *(const bf16x8*)(ab + SWZ(c, kb));
        bf16x8 bfv = *(const bf16x8*)(wb + SWZ(c, kb));
        acc = __builtin_amdgcn_mfma_f32_16x16x32_bf16(af, bfv, acc, 0, 0, 0);
      }
    }
    f32x4 zreg;
#pragma unroll
    for (int i = 0; i < 4; i++) {
      int row = q * 4 + i;
      int b = bg * 16 + row;
      float pre = acc[i] + gA[i];
      pre = fminf(fmaxf(pre, -30.f), 30.f);
      float sg = 1.f / (1.f + __expf(-pre));
      if (w < 2) {
        zreg[i] = sg;
      } else {
        float rh = sg * lds_hprev[row * 32 + sub * 16 + c];
        __hip_atomic_store(&RHst[((size_t)dir * 64 + b) * 512 + jn], f2bf(rh),
                           __ATOMIC_RELAXED, __HIP_MEMORY_SCOPE_AGENT);
      }
    }
    gbar(ctr, ep, tid);   // barrier 1: r*h exchange complete

    // stage A_rh
    {
      int row = tid & 15;
      int cb = (tid >> 4) * 64;
      const u32x4* src = (const u32x4*)((const char*)RHst +
                          ((size_t)(dir * 64 + bg * 16 + row) * 512) * 2 + cb);
      u32x4 v0 = src[0], v1 = src[1], v2 = src[2], v3 = src[3];
      char* dst = (char*)lds_arh;
      *(u32x4*)(dst + SWZ(row, cb + 0))  = v0;
      *(u32x4*)(dst + SWZ(row, cb + 16)) = v1;
      *(u32x4*)(dst + SWZ(row, cb + 32)) = v2;
      *(u32x4*)(dst + SWZ(row, cb + 48)) = v3;
    }
    __syncthreads();

    // P2: waves 0,1 compute h~ tiles (nt = 4+sub), pointwise, h update
    if (w < 2) {
      f32x4 acc2 = (f32x4){0.f, 0.f, 0.f, 0.f};
      const char* wb = (const char*)lds_w + (4 + sub) * 16384;
      const char* ab = (const char*)lds_arh;
#pragma unroll
      for (int ks = 0; ks < 16; ks++) {
        int kb = ks * 64 + q * 16;
        bf16x8 af = *(const bf16x8*)(ab + SWZ(c, kb));
        bf16x8 bfv = *(const bf16x8*)(wb + SWZ(c, kb));
        acc2 = __builtin_amdgcn_mfma_f32_16x16x32_bf16(af, bfv, acc2, 0, 0, 0);
      }
      float* op = dir ? Hb : outp;
#pragma unroll
      for (int i = 0; i < 4; i++) {
        int row = q * 4 + i;
        int b = bg * 16 + row;
        float pre = acc2[i] + gC[i];
        pre = fminf(fmaxf(pre, -15.f), 15.f);
        float e2 = __expf(2.f * pre);
        float th = (e2 - 1.f) / (e2 + 1.f);
        float hp = lds_hprev[row * 32 + sub * 16 + c];
        float z = zreg[i];
        float hn = (1.f - z) * hp + z * th;
        op[((size_t)b * TDIM + t) * HDIM + jn] = hn;
        __hip_atomic_store(&Hst[((size_t)dir * 64 + b) * 512 + jn], f2bf(hn),
                           __ATOMIC_RELAXED, __HIP_MEMORY_SCOPE_AGENT);
        lds_hprev[row * 32 + sub * 16 + c] = hn;
      }
    }
    gbar(ctr, ep, tid);   // barrier 2: h(t) published
  }
}

// ---------------- host ----------------

extern "C" void kernel_launch(void* const* d_in, const int* in_sizes, int n_in,
                              void* d_out, int out_size, void* d_ws, size_t ws_size,
                              hipStream_t stream) {
  (void)in_sizes; (void)n_in;
  const float* x  = (const float*)d_in[0];
  const float* h0 = (const float*)d_in[1];
  const float* Wz = (const float*)d_in[2];
  const float* bz = (const float*)d_in[3];
  const float* Wr = (const float*)d_in[4];
  const float* br = (const float*)d_in[5];
  const float* Wh = (const float*)d_in[6];
  const float* bh = (const float*)d_in[7];
  float* outp = (float*)d_out;

  const size_t szG16 = (size_t)32768 * 1536 * 2;
  const size_t szG32 = szG16 * 2;
  const size_t szXb  = (size_t)BDIM * TDIM * EDIM * 2;
  const size_t szW   = (size_t)3 * 512 * 512 * 2;
  const size_t szHb  = (size_t)BDIM * TDIM * HDIM * 4;
  const size_t szHst = (size_t)2 * 64 * 512 * 2;
  const size_t fixed = szXb + 2 * szW + szHb + 2 * szHst + 8192;

  int g32 = (ws_size >= fixed + szG32 + 4096) ? 1 : 0;
  if (ws_size < fixed + szG16 + 4096) {
    sentinel_kern<<<256, 256, 0, stream>>>(outp, out_size);
    return;
  }
  const size_t szG = g32 ? szG32 : szG16;

  size_t off = 0;
  char* base = (char*)d_ws;
  auto alloc = [&](size_t sz) { char* p = base + off; off = (off + sz + 255) & ~(size_t)255; return p; };
  void* G               = (void*)alloc(szG);
  unsigned short* xb    = (unsigned short*)alloc(szXb);
  unsigned short* Wxb   = (unsigned short*)alloc(szW);
  unsigned short* Whb   = (unsigned short*)alloc(szW);
  float* Hb             = (float*)alloc(szHb);
  unsigned short* Hst   = (unsigned short*)alloc(szHst);
  unsigned short* RHst  = (unsigned short*)alloc(szHst);
  unsigned int* ctrs    = (unsigned int*)alloc(4096);

  hipMemsetAsync(ctrs, 0, 4096, stream);
  conv_w<<<(3 * 512 * 1024 + 255) / 256, 256, 0, stream>>>(Wz, Wr, Wh, Wxb, Whb);
  conv_x<<<2048, 256, 0, stream>>>(x, xb, (BDIM * TDIM * EDIM) / 4);
  gru_xproj<<<dim3(256, 12), 256, 0, stream>>>(xb, Wxb, bz, br, bh, G, g32);
  gru_persist<<<128, 256, 0, stream>>>(G, g32, h0, Hst, RHst, ctrs, outp, Hb, Whb);
  add_out<<<2048, 256, 0, stream>>>(outp, Hb, (BDIM * TDIM * HDIM) / 4);
  hipMemcpyAsync(outp + (size_t)BDIM * TDIM * HDIM, h0,
                 (size_t)BDIM * HDIM * sizeof(float), hipMemcpyDeviceToDevice, stream);
}

// Round 2
// 4160.456 us; speedup vs baseline: 1.4133x; 1.4133x over previous
//
#include <hip/hip_runtime.h>
#include <stdint.h>

#define BDIM 64
#define TDIM 512
#define EDIM 512
#define HDIM 512

typedef __attribute__((ext_vector_type(8))) short bf16x8;
typedef __attribute__((ext_vector_type(4))) float f32x4;
typedef __attribute__((ext_vector_type(4))) unsigned int u32x4;
typedef __attribute__((ext_vector_type(4))) unsigned short u16x4;

static __device__ __forceinline__ unsigned short f2bf(float f) {
  union { float f; uint32_t u; } c; c.f = f;
  uint32_t u = c.u;
  uint32_t r = u + 0x7fffu + ((u >> 16) & 1u);
  return (unsigned short)(r >> 16);
}
static __device__ __forceinline__ float bf2f(unsigned short s) {
  union { uint32_t u; float f; } c; c.u = ((uint32_t)s) << 16;
  return c.f;
}

// swizzle for 1KB-row tiles (512 bf16 per row)
#define SWZ(row, byteInRow) ((((row)*1024) + (byteInRow)) ^ ((((row)&7))<<4))
// swizzle for 128B-row tiles (64 bf16 per row)
#define SWZA(row, byteInRow) ((((row)*128) + (byteInRow)) ^ ((((row)&7))<<4))

// ---------------- small utility kernels ----------------

__global__ void sentinel_kern(float* out, int n) {
  for (int i = blockIdx.x * blockDim.x + threadIdx.x; i < n; i += gridDim.x * blockDim.x)
    out[i] = -12345.0f;
}

__global__ void conv_w(const float* __restrict__ Wz, const float* __restrict__ Wr,
                       const float* __restrict__ Wh,
                       unsigned short* __restrict__ Wxb, unsigned short* __restrict__ Whb) {
  int idx = blockIdx.x * 256 + threadIdx.x;
  if (idx >= 3 * 512 * 1024) return;
  int g = idx >> 19;
  int rem = idx & 524287;
  int j = rem >> 10, k = rem & 1023;
  const float* W = (g == 0) ? Wz : (g == 1) ? Wr : Wh;
  unsigned short b = f2bf(W[(size_t)j * 1024 + k]);
  if (k < 512) Wxb[((size_t)g * 512 + j) * 512 + k] = b;
  else         Whb[((size_t)g * 512 + j) * 512 + (k - 512)] = b;
}

__global__ void conv_x(const float* __restrict__ x, unsigned short* __restrict__ xb, int n4) {
  for (int i = blockIdx.x * blockDim.x + threadIdx.x; i < n4; i += gridDim.x * blockDim.x) {
    f32x4 v = ((const f32x4*)x)[i];
    u16x4 o;
    o[0] = f2bf(v[0]); o[1] = f2bf(v[1]); o[2] = f2bf(v[2]); o[3] = f2bf(v[3]);
    ((u16x4*)xb)[i] = o;
  }
}

__global__ void add_out(float* __restrict__ out, const float* __restrict__ Hb, int n4) {
  for (int i = blockIdx.x * blockDim.x + threadIdx.x; i < n4; i += gridDim.x * blockDim.x) {
    f32x4 a = ((const f32x4*)out)[i];
    f32x4 b = ((const f32x4*)Hb)[i];
    ((f32x4*)out)[i] = a + b;
  }
}

// ---------------- phase A: G = x @ Wx^T + bias  (bf16 MFMA GEMM) ----------------
// M = B*T = 32768 (row m = b*T+t), N = 1536 (n = gate*512 + j), K = 512

__global__ __launch_bounds__(256, 2)
void gru_xproj(const unsigned short* __restrict__ xb,
               const unsigned short* __restrict__ Wxb,
               const float* __restrict__ bz, const float* __restrict__ br,
               const float* __restrict__ bh,
               void* __restrict__ Gv, int g32) {
  __shared__ __align__(16) unsigned short lA[128 * 64];
  __shared__ __align__(16) unsigned short lB[128 * 64];
  const int tid = threadIdx.x;
  const int m0 = blockIdx.x * 128;
  const int n0 = blockIdx.y * 128;
  const int w = tid >> 6, lane = tid & 63, cl = lane & 15, q = lane >> 4;
  const int wr = w >> 1, wc = w & 1;
  f32x4 acc[4][4];
#pragma unroll
  for (int i = 0; i < 4; i++)
#pragma unroll
    for (int j = 0; j < 4; j++) acc[i][j] = (f32x4){0.f, 0.f, 0.f, 0.f};

  for (int ko = 0; ko < 8; ko++) {
    int k0 = ko * 64;
#pragma unroll
    for (int cc = 0; cc < 4; cc++) {
      int qq = tid * 4 + cc;
      int row = qq >> 3, kc = qq & 7;
      u32x4 va = *(const u32x4*)(xb + ((size_t)(m0 + row) * EDIM + k0 + kc * 8));
      *(u32x4*)((char*)lA + SWZA(row, kc * 16)) = va;
      u32x4 vb = *(const u32x4*)(Wxb + ((size_t)(n0 + row) * EDIM + k0 + kc * 8));
      *(u32x4*)((char*)lB + SWZA(row, kc * 16)) = vb;
    }
    __syncthreads();
#pragma unroll
    for (int ks = 0; ks < 2; ks++) {
      bf16x8 af[4], bfv[4];
#pragma unroll
      for (int i = 0; i < 4; i++) {
        int rl = wr * 64 + i * 16 + cl;
        af[i] = *(const bf16x8*)((char*)lA + SWZA(rl, ks * 64 + q * 16));
      }
#pragma unroll
      for (int j = 0; j < 4; j++) {
        int rl = wc * 64 + j * 16 + cl;
        bfv[j] = *(const bf16x8*)((char*)lB + SWZA(rl, ks * 64 + q * 16));
      }
#pragma unroll
      for (int i = 0; i < 4; i++)
#pragma unroll
        for (int j = 0; j < 4; j++)
          acc[i][j] = __builtin_amdgcn_mfma_f32_16x16x32_bf16(af[i], bfv[j], acc[i][j], 0, 0, 0);
    }
    __syncthreads();
  }
  const int g = n0 >> 9;
  const float* bias = (g == 0) ? bz : (g == 1) ? br : bh;
  float* Gf = (float*)Gv;
  unsigned short* Gb = (unsigned short*)Gv;
#pragma unroll
  for (int i = 0; i < 4; i++) {
#pragma unroll
    for (int j = 0; j < 4; j++) {
      int n = n0 + wc * 64 + j * 16 + cl;
      float bv = bias[n & 511];
#pragma unroll
      for (int ii = 0; ii < 4; ii++) {
        int m = m0 + wr * 64 + i * 16 + q * 4 + ii;
        float v = acc[i][j][ii] + bv;
        size_t gi = (size_t)m * 1536 + n;
        if (g32) Gf[gi] = v; else Gb[gi] = f2bf(v);
      }
    }
  }
}

// ---------------- persistent bidirectional recurrence ----------------
// 128 wgs: bid = cg*8 + gid; gid = dir*4 + bg (8 groups of 16 wgs each).
// Per wg: batches bg*16..+15 (M=16), columns j0=cg*32..+31 for all 3 gates.
// Cross-wg exchange: RELAXED agent-scope atomics only (individually coherent
// at the LLC) — no acquire/release fences, so no per-step buffer_inv/wbl2
// L2 flushes. Ordering: each wave drains vmcnt(0) before s_barrier, so all
// data stores are acked at the coherence point before tid0 bumps the counter.

__device__ __forceinline__ void gbar(unsigned int* ctr, unsigned int& ep, int tid) {
  asm volatile("s_waitcnt vmcnt(0)" ::: "memory");
  __syncthreads();
  if (tid == 0) {
    ep++;
    unsigned int target = ep * 16u;
    __hip_atomic_fetch_add(ctr, 1u, __ATOMIC_RELAXED, __HIP_MEMORY_SCOPE_AGENT);
    while (__hip_atomic_load(ctr, __ATOMIC_RELAXED, __HIP_MEMORY_SCOPE_AGENT) < target) {}
  }
  __syncthreads();
}

__global__ __launch_bounds__(256, 1)
void gru_persist(const void* __restrict__ Gv, int g32,
                 const float* __restrict__ h0,
                 unsigned short* __restrict__ Hst,
                 unsigned short* __restrict__ RHst,
                 unsigned int* __restrict__ ctrs,
                 float* __restrict__ outp,
                 float* __restrict__ Hb,
                 const unsigned short* __restrict__ Whb) {
  __shared__ __align__(16) unsigned short lds_w[6 * 16 * 512];   // 96KB
  __shared__ __align__(16) unsigned short lds_ah[16 * 512];      // 16KB
  __shared__ __align__(16) unsigned short lds_arh[16 * 512];     // 16KB
  __shared__ float lds_hprev[16 * 32];                            // 2KB

  const int tid = threadIdx.x;
  const int bid = blockIdx.x;
  const int gid = bid & 7;
  const int cg = bid >> 3;
  const int dir = gid >> 2;
  const int bg = gid & 3;
  const int j0 = cg * 32;
  const int w = tid >> 6;
  const int lane = tid & 63;
  const int c = lane & 15;
  const int q = lane >> 4;
  unsigned int* ctr = &ctrs[gid * 32];

  // load weight tiles (one-time): nt = gate*2+sub, cols j0+sub*16+col
  for (int qk = tid; qk < 6144; qk += 256) {
    int nt = qk >> 10;
    int cin = qk & 1023;
    int col = cin & 15;
    int kc = cin >> 4;   // 0..63 (16B chunk)
    int g = nt >> 1, sub = nt & 1;
    int jglob = j0 + sub * 16 + col;
    u32x4 v = *(const u32x4*)(Whb + (((size_t)g * 512 + jglob) * 512 + kc * 8));
    *(u32x4*)((char*)lds_w + nt * 16384 + SWZ(col, kc * 16)) = v;
  }

  // init hprev (fp32, local cols) and Hst (bf16, LLC-coherent)
#pragma unroll
  for (int ii = 0; ii < 2; ii++) {
    int idx = tid * 2 + ii;
    int row = idx >> 5, jl = idx & 31;
    int b = bg * 16 + row, j = j0 + jl;
    float v = h0[(size_t)b * HDIM + j];
    lds_hprev[row * 32 + jl] = v;
    __hip_atomic_store(&Hst[((size_t)dir * 64 + b) * 512 + j], f2bf(v),
                       __ATOMIC_RELAXED, __HIP_MEMORY_SCOPE_AGENT);
  }

  unsigned int ep = 0;
  gbar(ctr, ep, tid);

  const float* Gf = (const float*)Gv;
  const unsigned short* Gb = (const unsigned short*)Gv;
  const int sub = w & 1;
  const int jn = j0 + sub * 16 + c;
  const int gateA = (w < 2) ? 0 : 1;

  for (int s = 0; s < TDIM; s++) {
    int t = dir ? (TDIM - 1 - s) : s;

    // prefetch G values for this step (independent of staging)
    f32x4 gA, gC;
#pragma unroll
    for (int i = 0; i < 4; i++) {
      int b = bg * 16 + q * 4 + i;
      size_t mrow = (size_t)b * TDIM + t;
      size_t giA = (mrow * 3 + gateA) * HDIM + jn;
      gA[i] = g32 ? Gf[giA] : bf2f(Gb[giA]);
      if (w < 2) {
        size_t giC = (mrow * 3 + 2) * HDIM + jn;
        gC[i] = g32 ? Gf[giC] : bf2f(Gb[giC]);
      }
    }

    // stage A_h (h state, bf16) into LDS — coherent 8B atomic loads
    {
      int row = tid & 15;
      int cb = (tid >> 4) * 64;
      const unsigned long long* src = (const unsigned long long*)((const char*)Hst +
                          ((size_t)(dir * 64 + bg * 16 + row) * 512) * 2 + cb);
      unsigned long long v[8];
#pragma unroll
      for (int i = 0; i < 8; i++)
        v[i] = __hip_atomic_load(&src[i], __ATOMIC_RELAXED, __HIP_MEMORY_SCOPE_AGENT);
      char* dst = (char*)lds_ah;
#pragma unroll
      for (int i = 0; i < 8; i++)
        *(unsigned long long*)(dst + SWZ(row, cb + i * 8)) = v[i];
    }
    __syncthreads();

    // P1: wave w computes tile nt=w (z: 0,1 ; r: 2,3), K=512
    // 4 independent accumulator chains to break MFMA latency serialization
    f32x4 a0 = (f32x4){0.f,0.f,0.f,0.f}, a1 = (f32x4){0.f,0.f,0.f,0.f};
    f32x4 a2 = (f32x4){0.f,0.f,0.f,0.f}, a3 = (f32x4){0.f,0.f,0.f,0.f};
    {
      const char* wb = (const char*)lds_w + w * 16384;
      const char* ab = (const char*)lds_ah;
#pragma unroll
      for (int ks = 0; ks < 4; ks++) {
#pragma unroll
        for (int p = 0; p < 4; p++) {
          int kb = (ks * 4 + p) * 64 + q * 16;
          bf16x8 af = *(const bf16x8*)(ab + SWZ(c, kb));
          bf16x8 bfv = *(const bf16x8*)(wb + SWZ(c, kb));
          if (p == 0) a0 = __builtin_amdgcn_mfma_f32_16x16x32_bf16(af, bfv, a0, 0, 0, 0);
          else if (p == 1) a1 = __builtin_amdgcn_mfma_f32_16x16x32_bf16(af, bfv, a1, 0, 0, 0);
          else if (p == 2) a2 = __builtin_amdgcn_mfma_f32_16x16x32_bf16(af, bfv, a2, 0, 0, 0);
          else a3 = __builtin_amdgcn_mfma_f32_16x16x32_bf16(af, bfv, a3, 0, 0, 0);
        }
      }
    }
    f32x4 acc = (a0 + a1) + (a2 + a3);
    f32x4 zreg;
#pragma unroll
    for (int i = 0; i < 4; i++) {
      int row = q * 4 + i;
      int b = bg * 16 + row;
      float pre = acc[i] + gA[i];
      pre = fminf(fmaxf(pre, -30.f), 30.f);
      float sg = 1.f / (1.f + __expf(-pre));
      if (w < 2) {
        zreg[i] = sg;
      } else {
        float rh = sg * lds_hprev[row * 32 + sub * 16 + c];
        __hip_atomic_store(&RHst[((size_t)dir * 64 + b) * 512 + jn], f2bf(rh),
                           __ATOMIC_RELAXED, __HIP_MEMORY_SCOPE_AGENT);
      }
    }
    gbar(ctr, ep, tid);   // barrier 1: r*h exchange complete

    // stage A_rh — coherent 8B atomic loads
    {
      int row = tid & 15;
      int cb = (tid >> 4) * 64;
      const unsigned long long* src = (const unsigned long long*)((const char*)RHst +
                          ((size_t)(dir * 64 + bg * 16 + row) * 512) * 2 + cb);
      unsigned long long v[8];
#pragma unroll
      for (int i = 0; i < 8; i++)
        v[i] = __hip_atomic_load(&src[i], __ATOMIC_RELAXED, __HIP_MEMORY_SCOPE_AGENT);
      char* dst = (char*)lds_arh;
#pragma unroll
      for (int i = 0; i < 8; i++)
        *(unsigned long long*)(dst + SWZ(row, cb + i * 8)) = v[i];
    }
    __syncthreads();

    // P2: waves 0,1 compute h~ tiles (nt = 4+sub), pointwise, h update
    if (w < 2) {
      f32x4 b0 = (f32x4){0.f,0.f,0.f,0.f}, b1 = (f32x4){0.f,0.f,0.f,0.f};
      f32x4 b2 = (f32x4){0.f,0.f,0.f,0.f}, b3 = (f32x4){0.f,0.f,0.f,0.f};
      const char* wb = (const char*)lds_w + (4 + sub) * 16384;
      const char* ab = (const char*)lds_arh;
#pragma unroll
      for (int ks = 0; ks < 4; ks++) {
#pragma unroll
        for (int p = 0; p < 4; p++) {
          int kb = (ks * 4 + p) * 64 + q * 16;
          bf16x8 af = *(const bf16x8*)(ab + SWZ(c, kb));
          bf16x8 bfv = *(const bf16x8*)(wb + SWZ(c, kb));
          if (p == 0) b0 = __builtin_amdgcn_mfma_f32_16x16x32_bf16(af, bfv, b0, 0, 0, 0);
          else if (p == 1) b1 = __builtin_amdgcn_mfma_f32_16x16x32_bf16(af, bfv, b1, 0, 0, 0);
          else if (p == 2) b2 = __builtin_amdgcn_mfma_f32_16x16x32_bf16(af, bfv, b2, 0, 0, 0);
          else b3 = __builtin_amdgcn_mfma_f32_16x16x32_bf16(af, bfv, b3, 0, 0, 0);
        }
      }
      f32x4 acc2 = (b0 + b1) + (b2 + b3);
      float* op = dir ? Hb : outp;
#pragma unroll
      for (int i = 0; i < 4; i++) {
        int row = q * 4 + i;
        int b = bg * 16 + row;
        float pre = acc2[i] + gC[i];
        pre = fminf(fmaxf(pre, -15.f), 15.f);
        float e2 = __expf(2.f * pre);
        float th = (e2 - 1.f) / (e2 + 1.f);
        float hp = lds_hprev[row * 32 + sub * 16 + c];
        float z = zreg[i];
        float hn = (1.f - z) * hp + z * th;
        op[((size_t)b * TDIM + t) * HDIM + jn] = hn;
        __hip_atomic_store(&Hst[((size_t)dir * 64 + b) * 512 + jn], f2bf(hn),
                           __ATOMIC_RELAXED, __HIP_MEMORY_SCOPE_AGENT);
        lds_hprev[row * 32 + sub * 16 + c] = hn;
      }
    }
    gbar(ctr, ep, tid);   // barrier 2: h(t) published
  }
}

// ---------------- host ----------------

extern "C" void kernel_launch(void* const* d_in, const int* in_sizes, int n_in,
                              void* d_out, int out_size, void* d_ws, size_t ws_size,
                              hipStream_t stream) {
  (void)in_sizes; (void)n_in;
  const float* x  = (const float*)d_in[0];
  const float* h0 = (const float*)d_in[1];
  const float* Wz = (const float*)d_in[2];
  const float* bz = (const float*)d_in[3];
  const float* Wr = (const float*)d_in[4];
  const float* br = (const float*)d_in[5];
  const float* Wh = (const float*)d_in[6];
  const float* bh = (const float*)d_in[7];
  float* outp = (float*)d_out;

  const size_t szG16 = (size_t)32768 * 1536 * 2;
  const size_t szG32 = szG16 * 2;
  const size_t szXb  = (size_t)BDIM * TDIM * EDIM * 2;
  const size_t szW   = (size_t)3 * 512 * 512 * 2;
  const size_t szHb  = (size_t)BDIM * TDIM * HDIM * 4;
  const size_t szHst = (size_t)2 * 64 * 512 * 2;
  const size_t fixed = szXb + 2 * szW + szHb + 2 * szHst + 8192;

  int g32 = (ws_size >= fixed + szG32 + 4096) ? 1 : 0;
  if (ws_size < fixed + szG16 + 4096) {
    sentinel_kern<<<256, 256, 0, stream>>>(outp, out_size);
    return;
  }
  const size_t szG = g32 ? szG32 : szG16;

  size_t off = 0;
  char* base = (char*)d_ws;
  auto alloc = [&](size_t sz) { char* p = base + off; off = (off + sz + 255) & ~(size_t)255; return p; };
  void* G               = (void*)alloc(szG);
  unsigned short* xb    = (unsigned short*)alloc(szXb);
  unsigned short* Wxb   = (unsigned short*)alloc(szW);
  unsigned short* Whb   = (unsigned short*)alloc(szW);
  float* Hb             = (float*)alloc(szHb);
  unsigned short* Hst   = (unsigned short*)alloc(szHst);
  unsigned short* RHst  = (unsigned short*)alloc(szHst);
  unsigned int* ctrs    = (unsigned int*)alloc(4096);

  hipMemsetAsync(ctrs, 0, 4096, stream);
  conv_w<<<(3 * 512 * 1024 + 255) / 256, 256, 0, stream>>>(Wz, Wr, Wh, Wxb, Whb);
  conv_x<<<2048, 256, 0, stream>>>(x, xb, (BDIM * TDIM * EDIM) / 4);
  gru_xproj<<<dim3(256, 12), 256, 0, stream>>>(xb, Wxb, bz, br, bh, G, g32);
  gru_persist<<<128, 256, 0, stream>>>(G, g32, h0, Hst, RHst, ctrs, outp, Hb, Whb);
  add_out<<<2048, 256, 0, stream>>>(outp, Hb, (BDIM * TDIM * HDIM) / 4);
  hipMemcpyAsync(outp + (size_t)BDIM * TDIM * HDIM, h0,
                 (size_t)BDIM * HDIM * sizeof(float), hipMemcpyDeviceToDevice, stream);
}